// Round 17
// baseline (173.129 us; speedup 1.0000x reference)
//
#include <hip/hip_runtime.h>

// ExpertModuleTrm: B=16, L=2048, D=400, HS=100, heads=4 (identical -> 1 head).
// R16: flash KV-split generalized to PARTS in {1,2,4} (ws-guarded). PARTS=4 ->
//   1024 blocks fills the 3rd residency slot (46KB LDS admits 3 blocks/CU but
//   512-block grid capped at 2/CU). hpool combine generalized to 4-way merge.
//   Everything else identical to R15 (163.5us best).

#define L_SEQ 2048
#define HS    100
#define ATT_SCALE_L2E 0.14426950408889634f
#define DEFER_THR 11.5416f   // 8 * log2(e)

typedef __attribute__((ext_vector_type(8))) short bf16x8;
typedef __attribute__((ext_vector_type(4))) float f32x4;
#define MFMA16 __builtin_amdgcn_mfma_f32_16x16x32_bf16

__device__ __forceinline__ ushort f2bf(float f) {   // fp32 -> bf16 RNE (finite)
    unsigned u = __float_as_uint(f);
    u += 0x7fffu + ((u >> 16) & 1u);
    return (ushort)(u >> 16);
}
__device__ __forceinline__ float bfval(ushort u) {
    return __uint_as_float((unsigned)u << 16);
}
__device__ __forceinline__ float exp2_hw(float x) {  // native 2^x
    float r;
    asm("v_exp_f32 %0, %1" : "=v"(r) : "v"(x));
    return r;
}

// ---- kernel 0: fused weight prep ----
__global__ __launch_bounds__(256)
void k_prep(const float* __restrict__ dense, const float* __restrict__ w2,
            const float* __restrict__ kw,
            ushort* __restrict__ WT_hi, ushort* __restrict__ WT_lo,
            ushort* __restrict__ wT_hi, ushort* __restrict__ wT_lo)
{
    __shared__ float rows[4 * 400];
    __shared__ float red[4][4][64];
    const int id = blockIdx.x;
    const int tid = threadIdx.x;
    if (id < 224) {
        const int cb = id % 7;
        const int r0 = (id / 7) * 4;
        const int c = tid & 63, kk = tid >> 6;
        const int col = cb * 64 + c;
        for (int i = tid; i < 1600; i += 256) {
            int rr = r0 + i / 400, cc = i - (i / 400) * 400;
            rows[i] = (rr < 100)
                ? dense[rr * 400 + cc] + dense[(rr + 100) * 400 + cc]
                  + dense[(rr + 200) * 400 + cc] + dense[(rr + 300) * 400 + cc]
                : 0.f;
        }
        __syncthreads();
        float a0 = 0.f, a1 = 0.f, a2 = 0.f, a3 = 0.f;
        if (col < 400) {
            const int kbase = kk * 100;
#pragma unroll 4
            for (int k = 0; k < 100; ++k) {
                float wv = w2[(kbase + k) * 400 + col];
                a0 += rows[kbase + k] * wv;
                a1 += rows[400 + kbase + k] * wv;
                a2 += rows[800 + kbase + k] * wv;
                a3 += rows[1200 + kbase + k] * wv;
            }
        }
        red[kk][0][c] = a0; red[kk][1][c] = a1; red[kk][2][c] = a2; red[kk][3][c] = a3;
        __syncthreads();
        {
            const int r = kk;
            float s = red[0][r][c] + red[1][r][c] + red[2][r][c] + red[3][r][c];
            ushort hi = f2bf(s);
            WT_hi[col * 128 + r0 + r] = hi;
            WT_lo[col * 128 + r0 + r] = f2bf(s - bfval(hi));
        }
    } else {
        const int j = id - 224;
        const int c = j >> 7, h = j & 127;
        for (int k = tid; k < 448; k += 256) {
            float v = 0.f;
            if (h < 100 && k < 400) v = kw[c * 40000 + k * 100 + h];
            if (c == 0) v *= ATT_SCALE_L2E;
            ushort hi = f2bf(v);
            wT_hi[(size_t)j * 448 + k] = hi;
            wT_lo[(size_t)j * 448 + k] = f2bf(v - bfval(hi));
        }
    }
}

// ---------------- kernel 1: MFMA QKV gemm (R15 geometry) ----------------
__global__ __launch_bounds__(512, 4)
void k_qkv(const float* __restrict__ x,
           const ushort* __restrict__ wT_hi, const ushort* __restrict__ wT_lo,
           ushort* __restrict__ q_hi, ushort* __restrict__ q_lo,
           ushort* __restrict__ k_hi, ushort* __restrict__ vT)
{
    __shared__ __align__(16) ushort xh_s[2][64 * 64];
    __shared__ __align__(16) ushort xl_s[2][64 * 64];
    const int row0 = blockIdx.x << 6;
    const int bb = row0 >> 11;
    const int tid = threadIdx.x;
    const int lane = tid & 63, wv = tid >> 6;
    const int q15 = lane & 15, g0 = lane >> 4;
    const int cW = wv * 48;

    f32x4 acc[3][4];
#pragma unroll
    for (int mf = 0; mf < 3; ++mf)
#pragma unroll
        for (int nf = 0; nf < 4; ++nf) acc[mf][nf] = (f32x4){0.f, 0.f, 0.f, 0.f};

    float4 st[2];
#define QKV_STAGE_LOAD(KC)                                                     \
    _Pragma("unroll") for (int i = 0; i < 2; ++i) {                            \
        int idx = tid + i * 512; int r = idx >> 4, c4 = idx & 15;              \
        int g = (KC) * 64 + c4 * 4;                                            \
        st[i] = (g <= 396) ? *reinterpret_cast<const float4*>(                 \
                                 &x[(size_t)(row0 + r) * 400 + g])             \
                           : make_float4(0.f, 0.f, 0.f, 0.f);                  \
    }
#define QKV_STAGE_WRITE(BUF)                                                   \
    _Pragma("unroll") for (int i = 0; i < 2; ++i) {                            \
        int idx = tid + i * 512; int r = idx >> 4, c4 = idx & 15;              \
        ushort4 hi4, lo4;                                                      \
        hi4.x = f2bf(st[i].x); lo4.x = f2bf(st[i].x - bfval(hi4.x));           \
        hi4.y = f2bf(st[i].y); lo4.y = f2bf(st[i].y - bfval(hi4.y));           \
        hi4.z = f2bf(st[i].z); lo4.z = f2bf(st[i].z - bfval(hi4.z));           \
        hi4.w = f2bf(st[i].w); lo4.w = f2bf(st[i].w - bfval(hi4.w));           \
        int off = r * 128 + ((c4 * 8) ^ ((r & 7) << 4));                       \
        *reinterpret_cast<ushort4*>((char*)xh_s[BUF] + off) = hi4;             \
        *reinterpret_cast<ushort4*>((char*)xl_s[BUF] + off) = lo4;             \
    }

    QKV_STAGE_LOAD(0)
    QKV_STAGE_WRITE(0)
    __syncthreads();

    for (int kc = 0; kc < 7; ++kc) {
        const int cur = kc & 1;
        if (kc < 6) { QKV_STAGE_LOAD(kc + 1) }
#pragma unroll
        for (int k2 = 0; k2 < 2; ++k2) {
            const int k0 = kc * 64 + k2 * 32;
            bf16x8 bh[4], bl[4];
#pragma unroll
            for (int nf = 0; nf < 4; ++nf) {
                int row = nf * 16 + q15;
                int boff = row * 128 + ((k2 * 64 + g0 * 16) ^ ((row & 7) << 4));
                bh[nf] = *reinterpret_cast<const bf16x8*>((char*)xh_s[cur] + boff);
                bl[nf] = *reinterpret_cast<const bf16x8*>((char*)xl_s[cur] + boff);
            }
#pragma unroll
            for (int mf = 0; mf < 3; ++mf) {
                int col = cW + mf * 16 + q15;
                bf16x8 ah = *reinterpret_cast<const bf16x8*>(
                    wT_hi + (size_t)col * 448 + k0 + g0 * 8);
                bf16x8 al = *reinterpret_cast<const bf16x8*>(
                    wT_lo + (size_t)col * 448 + k0 + g0 * 8);
#pragma unroll
                for (int nf = 0; nf < 4; ++nf) {
                    acc[mf][nf] = MFMA16(ah, bh[nf], acc[mf][nf], 0, 0, 0);
                    acc[mf][nf] = MFMA16(ah, bl[nf], acc[mf][nf], 0, 0, 0);
                    acc[mf][nf] = MFMA16(al, bh[nf], acc[mf][nf], 0, 0, 0);
                }
            }
        }
        if (kc < 6) {
            QKV_STAGE_WRITE(cur ^ 1)
            __syncthreads();
        }
    }

#pragma unroll
    for (int mf = 0; mf < 3; ++mf) {
        const int col0 = cW + mf * 16 + 4 * g0;
        const int c = col0 >> 7, h0 = col0 & 127;
#pragma unroll
        for (int nf = 0; nf < 4; ++nf) {
            const size_t row = (size_t)(row0 + nf * 16 + q15);
            if (c == 0) {
                ushort4 hi4, lo4;
#pragma unroll
                for (int r = 0; r < 4; ++r) {
                    float vf = acc[mf][nf][r];
                    ushort h = f2bf(vf);
                    ((ushort*)&hi4)[r] = h;
                    ((ushort*)&lo4)[r] = f2bf(vf - bfval(h));
                }
                *reinterpret_cast<ushort4*>(&q_hi[row * 128 + h0]) = hi4;
                *reinterpret_cast<ushort4*>(&q_lo[row * 128 + h0]) = lo4;
            } else if (c == 1) {
                ushort4 hi4;
#pragma unroll
                for (int r = 0; r < 4; ++r) ((ushort*)&hi4)[r] = f2bf(acc[mf][nf][r]);
                *reinterpret_cast<ushort4*>(&k_hi[row * 128 + h0]) = hi4;
            } else {
                const int keyl = (int)row & 2047;
#pragma unroll
                for (int jj = 0; jj < 4; ++jj) {
                    int h = h0 + jj;
                    if (h < 100)
                        vT[((size_t)bb * 112 + h) * 2048 + keyl] = f2bf(acc[mf][nf][jj]);
                }
            }
        }
    }
#undef QKV_STAGE_LOAD
#undef QKV_STAGE_WRITE
}

// ---------------- kernel 2: MFMA flash attention, QBLK=128, PARTS-way KV split ----------------
template<int PARTS>
__global__ __launch_bounds__(512, 2)
void k_flashT(const ushort* __restrict__ q_hi, const ushort* __restrict__ q_lo,
              const ushort* __restrict__ k_hi, const ushort* __restrict__ vT,
              float* __restrict__ outp, float2* __restrict__ mlP)
{
    __shared__ __align__(16) ushort k_s[64 * 128];    // 16 KB
    __shared__ __align__(16) ushort vT_s[112 * 64];   // 14 KB
    __shared__ __align__(16) ushort p_s[8][16 * 64];  // 16 KB

    const int id = blockIdx.x;                 // XCD-aware swizzle
    const int NB8 = 32 * PARTS;                // blocks per XCD slice
    const int Lg = (id & 7) * NB8 + (id >> 3);
    const int b = Lg / (16 * PARTS);
    const int rem = Lg % (16 * PARTS);
    const int qt = rem / PARTS, part = rem % PARTS;
    const int q0 = qt * 128;
    const size_t bL = (size_t)b * L_SEQ;
    const int ktBeg = part * (32 / PARTS), ktEnd = ktBeg + (32 / PARTS);

    const int tid = threadIdx.x;
    const int lane = tid & 63, wv = tid >> 6;        // wv 0..7
    const int q15 = lane & 15, g0 = lane >> 4;

    bf16x8 qhf[4], qlf[4];
    {
        const ushort* qr = q_hi + (bL + q0 + 16 * wv + q15) * 128 + 8 * g0;
        const ushort* qs = q_lo + (bL + q0 + 16 * wv + q15) * 128 + 8 * g0;
#pragma unroll
        for (int kh = 0; kh < 4; ++kh) {
            qhf[kh] = *reinterpret_cast<const bf16x8*>(qr + 32 * kh);
            qlf[kh] = *reinterpret_cast<const bf16x8*>(qs + 32 * kh);
        }
    }

    float m_run = -1e30f, l_run = 0.f;
    f32x4 acc[7];
#pragma unroll
    for (int ht = 0; ht < 7; ++ht) acc[ht] = (f32x4){0.f, 0.f, 0.f, 0.f};

    for (int kt = ktBeg; kt < ktEnd; ++kt) {
        const int kb = kt * 64;
        __syncthreads();                               // prev compute done
        {   // stage K tile [64][128] bf16, swizzled granules
            const char* khg = (const char*)(k_hi + (bL + kb) * 128);
            for (int n = tid; n < 1024; n += 512) {
                int key = n >> 4, gg = n & 15;
                uint4 d = *reinterpret_cast<const uint4*>(khg + n * 16);
                *reinterpret_cast<uint4*>((char*)k_s + key * 256 + (((gg ^ (key & 15))) << 4)) = d;
            }
            const char* vtg = (const char*)(vT + (size_t)b * 112 * 2048) + kb * 2;
            for (int n = tid; n < 896; n += 512) {
                int h = n >> 3, gg = n & 7;
                uint4 d = *reinterpret_cast<const uint4*>(vtg + h * 4096 + gg * 16);
                *reinterpret_cast<uint4*>((char*)vT_s + h * 128 + (((gg ^ (h & 7))) << 4)) = d;
            }
        }
        __syncthreads();

        // S^T = mfma(A=K, B=Q)
        f32x4 sacc[4];
        const int kx = q15 << 4;
        __builtin_amdgcn_s_setprio(1);
#pragma unroll
        for (int t = 0; t < 4; ++t) {
            sacc[t] = (f32x4){0.f, 0.f, 0.f, 0.f};
            const char* kr = (const char*)k_s + (t * 16 + q15) * 256;
#pragma unroll
            for (int kh = 0; kh < 4; ++kh) {
                bf16x8 kf = *reinterpret_cast<const bf16x8*>(kr + ((((kh << 2) + g0) << 4) ^ kx));
                sacc[t] = MFMA16(kf, qhf[kh], sacc[t], 0, 0, 0);
                sacc[t] = MFMA16(kf, qlf[kh], sacc[t], 0, 0, 0);
            }
        }
        __builtin_amdgcn_s_setprio(0);

        // online softmax, exp2 domain, defer-max (THR = 8*log2e)
        float mxl = -1e30f;
#pragma unroll
        for (int t = 0; t < 4; ++t)
#pragma unroll
            for (int r = 0; r < 4; ++r) mxl = fmaxf(mxl, sacc[t][r]);
        mxl = fmaxf(mxl, __shfl_xor(mxl, 16));
        mxl = fmaxf(mxl, __shfl_xor(mxl, 32));
        if (!__all(mxl - m_run <= DEFER_THR)) {
            float mn = fmaxf(m_run, mxl);
            float alpha = exp2_hw(m_run - mn);
            l_run *= alpha;
            m_run = mn;
            float alv[4];
#pragma unroll
            for (int r = 0; r < 4; ++r) alv[r] = __shfl(alpha, (g0 << 2) | r);
#pragma unroll
            for (int ht = 0; ht < 7; ++ht)
#pragma unroll
                for (int r = 0; r < 4; ++r) acc[ht][r] *= alv[r];
        }
        float lsum = 0.f;
        float p[4][4];
#pragma unroll
        for (int t = 0; t < 4; ++t)
#pragma unroll
            for (int r = 0; r < 4; ++r) {
                p[t][r] = exp2_hw(sacc[t][r] - m_run);
                lsum += p[t][r];
            }
        lsum += __shfl_xor(lsum, 16);
        lsum += __shfl_xor(lsum, 32);
        l_run += lsum;

        // P -> LDS (bf16 via v_cvt_pk_bf16_f32), per-wave region
        ushort* pw = p_s[wv];
        const int qb = q15 * 128;
#pragma unroll
        for (int t = 0; t < 4; ++t) {
            uint2 pv;
            asm("v_cvt_pk_bf16_f32 %0, %1, %2" : "=v"(pv.x) : "v"(p[t][0]), "v"(p[t][1]));
            asm("v_cvt_pk_bf16_f32 %0, %1, %2" : "=v"(pv.y) : "v"(p[t][2]), "v"(p[t][3]));
            int gw = (t << 1) + (g0 >> 1);
            *reinterpret_cast<uint2*>((char*)pw + qb + (((gw ^ (q15 & 7))) << 4)
                                      + ((g0 & 1) << 3)) = pv;
        }

        // PV
        bf16x8 pa0 = *reinterpret_cast<const bf16x8*>((char*)pw + qb + (((g0 ^ (q15 & 7))) << 4));
        bf16x8 pa1 = *reinterpret_cast<const bf16x8*>((char*)pw + qb + ((((4 + g0) ^ (q15 & 7))) << 4));
        __builtin_amdgcn_s_setprio(1);
#pragma unroll
        for (int ht = 0; ht < 7; ++ht) {
            const char* vr = (const char*)vT_s + (ht * 16 + q15) * 128;
            const int hx = ((ht * 16 + q15) & 7) << 4;
            bf16x8 vb0 = *reinterpret_cast<const bf16x8*>(vr + ((g0 << 4) ^ hx));
            bf16x8 vb1 = *reinterpret_cast<const bf16x8*>(vr + (((4 + g0) << 4) ^ hx));
            acc[ht] = MFMA16(pa0, vb0, acc[ht], 0, 0, 0);
            acc[ht] = MFMA16(pa1, vb1, acc[ht], 0, 0, 0);
        }
        __builtin_amdgcn_s_setprio(0);
    }

    if (PARTS > 1) {
        float* ap = outp + (size_t)part * 3276800
                    + (bL + q0 + 16 * wv + (g0 << 2)) * 100;
#pragma unroll
        for (int ht = 0; ht < 7; ++ht) {
            int col = ht * 16 + q15;
            if (col < 100) {
#pragma unroll
                for (int r = 0; r < 4; ++r) ap[r * 100 + col] = acc[ht][r];
            }
        }
        if (g0 == 0) {
            float2 ml; ml.x = m_run; ml.y = l_run;   // m in log2 domain
            mlP[(size_t)part * 32768 + bL + q0 + 16 * wv + q15] = ml;
        }
    } else {
        float linv[4];
#pragma unroll
        for (int r = 0; r < 4; ++r) linv[r] = 1.0f / __shfl(l_run, (g0 << 2) | r);
#pragma unroll
        for (int ht = 0; ht < 7; ++ht) {
            int col = ht * 16 + q15;
            if (col < 100) {
                float* hp = outp + (bL + q0 + 16 * wv + (g0 << 2)) * 100 + col;
#pragma unroll
                for (int r = 0; r < 4; ++r) hp[r * 100] = acc[ht][r] * linv[r];
            }
        }
    }
}

// ---------------- kernel 3: MFMA hpool; PARTS-way fused flash combine ----------------
template<int PARTS>
__global__ __launch_bounds__(512, 2)
void k_hpoolT(const float* __restrict__ accP, const float2* __restrict__ mlP,
              const ushort* __restrict__ WT_hi, const ushort* __restrict__ WT_lo,
              const float* __restrict__ b2,
              float* __restrict__ pmax, float* __restrict__ psum)
{
    __shared__ __align__(16) ushort hh_s[128 * 128];
    __shared__ __align__(16) ushort hl_s[128 * 128];
    __shared__ float pm_s[8][112], ps_s[8][112];
    const int blk = blockIdx.x;
    const int row0 = blk << 7;
    const int tid = threadIdx.x;
    const int lane = tid & 63, wv = tid >> 6;
    const int q15 = lane & 15, g0 = lane >> 4;
    const int wvM = wv >> 2, wvN = wv & 3;

    for (int i = 0; i < 7; ++i) {                 // stage head -> hi/lo LDS
        int idx = tid + i * 512;
        if (idx < 3200) {
            int r = idx / 25, cc = idx - r * 25;
            const size_t row = (size_t)(row0 + r);
            float4 t;
            if (PARTS > 1) {
                float2 ml[PARTS];
                float M = -1e30f;
#pragma unroll
                for (int p = 0; p < PARTS; ++p) {
                    ml[p] = mlP[(size_t)p * 32768 + row];
                    M = fmaxf(M, ml[p].x);
                }
                float w[PARTS], den = 0.f;
#pragma unroll
                for (int p = 0; p < PARTS; ++p) {
                    w[p] = exp2_hw(ml[p].x - M);
                    den += w[p] * ml[p].y;
                }
                float inv = 1.0f / den;
                t = make_float4(0.f, 0.f, 0.f, 0.f);
#pragma unroll
                for (int p = 0; p < PARTS; ++p) {
                    float wp = w[p] * inv;
                    float4 a = *reinterpret_cast<const float4*>(
                        &accP[(size_t)p * 3276800 + row * 100 + cc * 4]);
                    t.x += wp * a.x; t.y += wp * a.y;
                    t.z += wp * a.z; t.w += wp * a.w;
                }
            } else {
                t = *reinterpret_cast<const float4*>(&accP[row * 100 + cc * 4]);
            }
            ushort4 hi4, lo4;
            hi4.x = f2bf(t.x); lo4.x = f2bf(t.x - bfval(hi4.x));
            hi4.y = f2bf(t.y); lo4.y = f2bf(t.y - bfval(hi4.y));
            hi4.z = f2bf(t.z); lo4.z = f2bf(t.z - bfval(hi4.z));
            hi4.w = f2bf(t.w); lo4.w = f2bf(t.w - bfval(hi4.w));
            int off = r * 256 + ((cc * 8) ^ ((r & 7) << 4));
            *reinterpret_cast<ushort4*>((char*)hh_s + off) = hi4;
            *reinterpret_cast<ushort4*>((char*)hl_s + off) = lo4;
        }
    }
    for (int idx = tid; idx < 896; idx += 512) {  // zero-pad k 100..127
        int r = idx / 7, c7 = idx - (idx / 7) * 7;
        int off = r * 256 + (((200 + c7 * 8)) ^ ((r & 7) << 4));
        ushort4 z = {0, 0, 0, 0};
        *reinterpret_cast<ushort4*>((char*)hh_s + off) = z;
        *reinterpret_cast<ushort4*>((char*)hl_s + off) = z;
    }
    __syncthreads();

    f32x4 acc[4][7];
#pragma unroll
    for (int mf = 0; mf < 4; ++mf)
#pragma unroll
        for (int nf = 0; nf < 7; ++nf) acc[mf][nf] = (f32x4){0.f, 0.f, 0.f, 0.f};

#pragma unroll
    for (int ks = 0; ks < 4; ++ks) {
        const int k0 = ks * 32;
        bf16x8 ah[4], al[4];
#pragma unroll
        for (int mf = 0; mf < 4; ++mf) {
            int rowL = wvM * 64 + mf * 16 + q15;
            int aoff = rowL * 256 + ((k0 * 2 + g0 * 16) ^ ((rowL & 7) << 4));
            ah[mf] = *reinterpret_cast<const bf16x8*>((char*)hh_s + aoff);
            al[mf] = *reinterpret_cast<const bf16x8*>((char*)hl_s + aoff);
        }
#pragma unroll
        for (int nf = 0; nf < 7; ++nf) {
            int col = wvN * 112 + nf * 16 + q15;
            bf16x8 bh = *reinterpret_cast<const bf16x8*>(WT_hi + col * 128 + k0 + g0 * 8);
            bf16x8 bl = *reinterpret_cast<const bf16x8*>(WT_lo + col * 128 + k0 + g0 * 8);
#pragma unroll
            for (int mf = 0; mf < 4; ++mf) {
                acc[mf][nf] = MFMA16(ah[mf], bh, acc[mf][nf], 0, 0, 0);
                acc[mf][nf] = MFMA16(ah[mf], bl, acc[mf][nf], 0, 0, 0);
                acc[mf][nf] = MFMA16(al[mf], bh, acc[mf][nf], 0, 0, 0);
            }
        }
    }

#pragma unroll
    for (int nf = 0; nf < 7; ++nf) {
        int col = wvN * 112 + nf * 16 + q15;
        float bv = (col < 400) ? b2[col] : 0.f;
        float mx = 0.f, sm = 0.f;
#pragma unroll
        for (int mf = 0; mf < 4; ++mf)
#pragma unroll
            for (int r = 0; r < 4; ++r) {
                float hv = fmaxf(acc[mf][nf][r] + bv, 0.f);
                mx = fmaxf(mx, hv); sm += hv;
            }
        mx = fmaxf(mx, __shfl_xor(mx, 16));
        mx = fmaxf(mx, __shfl_xor(mx, 32));
        sm += __shfl_xor(sm, 16);
        sm += __shfl_xor(sm, 32);
        if (g0 == 0) {
            pm_s[wv][nf * 16 + q15] = mx;
            ps_s[wv][nf * 16 + q15] = sm;
        }
    }
    __syncthreads();
    if (tid < 448) {
        int wn = tid / 112, cc = tid - wn * 112;
        float mx = fmaxf(pm_s[wn][cc], pm_s[4 + wn][cc]);
        float sm = ps_s[wn][cc] + ps_s[4 + wn][cc];
        if (tid < 400) {
            pmax[blk * 400 + tid] = mx;
            psum[blk * 400 + tid] = sm;
        }
    }
}

// ---------------- kernel 4a: reduce 16 partials -> zin[16][800] ----------------
__global__ __launch_bounds__(512)
void k_reduce(const float* __restrict__ pmax, const float* __restrict__ psum,
              float* __restrict__ zin)
{
    const int b = blockIdx.x, c = threadIdx.x;
    if (c < 400) {
        float m = 0.f, s = 0.f;
#pragma unroll
        for (int tt = 0; tt < 16; ++tt) {
            m = fmaxf(m, pmax[(b * 16 + tt) * 400 + c]);
            s += psum[(b * 16 + tt) * 400 + c];
        }
        zin[b * 800 + c] = m;
        zin[b * 800 + 400 + c] = s * (1.0f / 2048.0f);
    }
}

// ---------------- kernel 4b: z1 = relu(zin @ w3 + b3), split-k x8 ----------------
__global__ __launch_bounds__(512)
void k_mlp1(const float* __restrict__ zin, const float* __restrict__ w3,
            const float* __restrict__ b3, float* __restrict__ z1)
{
    __shared__ float zs[800];
    __shared__ float red[8][64];
    const int cb = blockIdx.x, b = blockIdx.y;
    const int tid = threadIdx.x;
    const int c = tid & 63, kk = tid >> 6;
    const int col = cb * 64 + c;
    for (int i = tid; i < 800; i += 512) zs[i] = zin[b * 800 + i];
    __syncthreads();
    float acc = 0.f;
    const int k0 = kk * 100;
#pragma unroll 4
    for (int k = 0; k < 100; ++k)
        acc += zs[k0 + k] * w3[(k0 + k) * 512 + col];
    red[kk][c] = acc;
    __syncthreads();
    if (kk == 0) {
        float a = b3[col];
#pragma unroll
        for (int g = 0; g < 8; ++g) a += red[g][c];
        z1[b * 512 + col] = fmaxf(a, 0.f);
    }
}

// ---------------- kernel 4c: out = relu(z1 @ w4 + b4), split-k x8 ----------------
__global__ __launch_bounds__(512)
void k_mlp2(const float* __restrict__ z1, const float* __restrict__ w4,
            const float* __restrict__ b4, float* __restrict__ out)
{
    __shared__ float zs[512];
    __shared__ float red[8][64];
    const int cb = blockIdx.x, b = blockIdx.y;
    const int tid = threadIdx.x;
    const int c = tid & 63, kk = tid >> 6;
    const int col = cb * 64 + c;
    if (tid < 512) zs[tid] = z1[b * 512 + tid];
    __syncthreads();
    float acc = 0.f;
    const int k0 = kk * 64;
#pragma unroll 4
    for (int k = 0; k < 64; ++k)
        acc += zs[k0 + k] * w4[(k0 + k) * 256 + col];
    red[kk][c] = acc;
    __syncthreads();
    if (kk == 0) {
        float a = b4[col];
#pragma unroll
        for (int g = 0; g < 8; ++g) a += red[g][c];
        out[b * 256 + col] = fmaxf(a, 0.f);
    }
}

extern "C" void kernel_launch(void* const* d_in, const int* in_sizes, int n_in,
                              void* d_out, int out_size, void* d_ws, size_t ws_size,
                              hipStream_t stream) {
    (void)in_sizes; (void)n_in; (void)out_size;
    const float* x     = (const float*)d_in[0];
    const float* kw    = (const float*)d_in[1];
    const float* dense = (const float*)d_in[2];
    const float* w2    = (const float*)d_in[3];
    const float* b2    = (const float*)d_in[4];
    const float* w3    = (const float*)d_in[5];
    const float* b3    = (const float*)d_in[6];
    const float* w4    = (const float*)d_in[7];
    const float* b4    = (const float*)d_in[8];
    float* ws = (float*)d_ws;
    // fixed layout (float units):
    ushort* q_hi = (ushort*)(ws);                 // [32768][128] bf16
    ushort* q_lo = (ushort*)(ws + 2097152);
    ushort* k_hi = (ushort*)(ws + 4194304);
    ushort* vT   = (ushort*)(ws + 6291456);       // [16][112][2048] bf16
    float*  head = ws + 8126464;                  // [32768][100] f32 (= accP part 0)
    ushort* wT_hi = (ushort*)(ws + 8126464);      // overlays head; dead before flash
    ushort* wT_lo = (ushort*)(ws + 8212480);
    float*  pmax = ws;                            // overlays q_hi (dead after flash)
    float*  psum = ws + 2097152;
    float*  zin  = ws + 4194304;
    float*  z1   = ws + 4207104;
    float*  outp = (float*)d_out;
    float*  accP = head;                          // part0 == head

    // tier selection by workspace size (floats):
    //   4-way: accP[4] ends 21233664; mlP 262144; WT 57344 -> need 21553152
    //   2-way: need 14999552 (R15 layout)
    const bool p4 = ws_size >= (size_t)21553152 * sizeof(float);
    const bool p2 = !p4 && ws_size >= (size_t)14999552 * sizeof(float);
    float2* mlP   = (float2*)(ws + (p4 ? 21233664 : 14680064));
    ushort* WT_hi = (ushort*)(ws + (p4 ? 21495808 : (p2 ? 14942208 : 11403264)));
    ushort* WT_lo = WT_hi + 57344;

    k_prep  <<<dim3(608),      dim3(256), 0, stream>>>(dense, w2, kw,
                                                       WT_hi, WT_lo, wT_hi, wT_lo);
    k_qkv   <<<dim3(512),      dim3(512), 0, stream>>>(x, wT_hi, wT_lo,
                                                       q_hi, q_lo, k_hi, vT);
    if (p4) {
        k_flashT<4> <<<dim3(1024), dim3(512), 0, stream>>>(q_hi, q_lo, k_hi, vT,
                                                           accP, mlP);
        k_hpoolT<4> <<<dim3(256),  dim3(512), 0, stream>>>(accP, mlP,
                                                           WT_hi, WT_lo, b2,
                                                           pmax, psum);
    } else if (p2) {
        k_flashT<2> <<<dim3(512),  dim3(512), 0, stream>>>(q_hi, q_lo, k_hi, vT,
                                                           accP, mlP);
        k_hpoolT<2> <<<dim3(256),  dim3(512), 0, stream>>>(accP, mlP,
                                                           WT_hi, WT_lo, b2,
                                                           pmax, psum);
    } else {
        k_flashT<1> <<<dim3(256),  dim3(512), 0, stream>>>(q_hi, q_lo, k_hi, vT,
                                                           head, nullptr);
        k_hpoolT<1> <<<dim3(256),  dim3(512), 0, stream>>>(head, nullptr,
                                                           WT_hi, WT_lo, b2,
                                                           pmax, psum);
    }
    k_reduce<<<dim3(16),       dim3(512), 0, stream>>>(pmax, psum, zin);
    k_mlp1  <<<dim3(8, 16),    dim3(512), 0, stream>>>(zin, w3, b3, z1);
    k_mlp2  <<<dim3(4, 16),    dim3(512), 0, stream>>>(z1, w4, b4, outp);
}

// Round 18
// 163.482 us; speedup vs baseline: 1.0590x; 1.0590x over previous
//
#include <hip/hip_runtime.h>

// ExpertModuleTrm: B=16, L=2048, D=400, HS=100, heads=4 (identical -> 1 head).
// R17 = R15 exactly (best measured: 163.5us). R16's 4-way KV split confirmed
//   the runtime won't co-schedule >~94KB LDS/CU for 512-thr blocks (3rd block
//   never resident; occupancy flat at ~38%) and regressed to 173us. Converged:
//   every structural lever (prefetch-in-regs, barrier removal, tile reshape,
//   occupancy splits) has been measured; this config is the fixed point.

#define L_SEQ 2048
#define HS    100
#define ATT_SCALE_L2E 0.14426950408889634f
#define DEFER_THR 11.5416f   // 8 * log2(e)

typedef __attribute__((ext_vector_type(8))) short bf16x8;
typedef __attribute__((ext_vector_type(4))) float f32x4;
#define MFMA16 __builtin_amdgcn_mfma_f32_16x16x32_bf16

__device__ __forceinline__ ushort f2bf(float f) {   // fp32 -> bf16 RNE (finite)
    unsigned u = __float_as_uint(f);
    u += 0x7fffu + ((u >> 16) & 1u);
    return (ushort)(u >> 16);
}
__device__ __forceinline__ float bfval(ushort u) {
    return __uint_as_float((unsigned)u << 16);
}
__device__ __forceinline__ float exp2_hw(float x) {  // native 2^x
    float r;
    asm("v_exp_f32 %0, %1" : "=v"(r) : "v"(x));
    return r;
}

// ---- kernel 0: fused weight prep. Blocks 0..223: WT = ((sum_r dense)@w2)^T
//      hi/lo [448][128]. Blocks 224..607: wT[j][k] from kernel[3][400][100]. ----
__global__ __launch_bounds__(256)
void k_prep(const float* __restrict__ dense, const float* __restrict__ w2,
            const float* __restrict__ kw,
            ushort* __restrict__ WT_hi, ushort* __restrict__ WT_lo,
            ushort* __restrict__ wT_hi, ushort* __restrict__ wT_lo)
{
    __shared__ float rows[4 * 400];
    __shared__ float red[4][4][64];
    const int id = blockIdx.x;
    const int tid = threadIdx.x;
    if (id < 224) {
        const int cb = id % 7;            // col group, 64 wide
        const int r0 = (id / 7) * 4;      // 0..124
        const int c = tid & 63, kk = tid >> 6;
        const int col = cb * 64 + c;
        for (int i = tid; i < 1600; i += 256) {
            int rr = r0 + i / 400, cc = i - (i / 400) * 400;
            rows[i] = (rr < 100)
                ? dense[rr * 400 + cc] + dense[(rr + 100) * 400 + cc]
                  + dense[(rr + 200) * 400 + cc] + dense[(rr + 300) * 400 + cc]
                : 0.f;
        }
        __syncthreads();
        float a0 = 0.f, a1 = 0.f, a2 = 0.f, a3 = 0.f;
        if (col < 400) {
            const int kbase = kk * 100;
#pragma unroll 4
            for (int k = 0; k < 100; ++k) {
                float wv = w2[(kbase + k) * 400 + col];
                a0 += rows[kbase + k] * wv;
                a1 += rows[400 + kbase + k] * wv;
                a2 += rows[800 + kbase + k] * wv;
                a3 += rows[1200 + kbase + k] * wv;
            }
        }
        red[kk][0][c] = a0; red[kk][1][c] = a1; red[kk][2][c] = a2; red[kk][3][c] = a3;
        __syncthreads();
        {
            const int r = kk;
            float s = red[0][r][c] + red[1][r][c] + red[2][r][c] + red[3][r][c];
            ushort hi = f2bf(s);
            WT_hi[col * 128 + r0 + r] = hi;
            WT_lo[col * 128 + r0 + r] = f2bf(s - bfval(hi));
        }
    } else {
        const int j = id - 224;           // 0..383
        const int c = j >> 7, h = j & 127;
        for (int k = tid; k < 448; k += 256) {
            float v = 0.f;
            if (h < 100 && k < 400) v = kw[c * 40000 + k * 100 + h];
            if (c == 0) v *= ATT_SCALE_L2E;
            ushort hi = f2bf(v);
            wT_hi[(size_t)j * 448 + k] = hi;
            wT_lo[(size_t)j * 448 + k] = f2bf(v - bfval(hi));
        }
    }
}

// ---------------- kernel 1: MFMA QKV gemm, 512 blocks x (64 rows x 384 cols) ----------------
// 8 waves = 8 colgroups(48=3mf) x 1 rowgroup(64=4nf). LDS 32KB dbuf -> 2 blocks/CU.
__global__ __launch_bounds__(512, 4)
void k_qkv(const float* __restrict__ x,
           const ushort* __restrict__ wT_hi, const ushort* __restrict__ wT_lo,
           ushort* __restrict__ q_hi, ushort* __restrict__ q_lo,
           ushort* __restrict__ k_hi, ushort* __restrict__ vT)
{
    __shared__ __align__(16) ushort xh_s[2][64 * 64];
    __shared__ __align__(16) ushort xl_s[2][64 * 64];
    const int row0 = blockIdx.x << 6;
    const int bb = row0 >> 11;
    const int tid = threadIdx.x;
    const int lane = tid & 63, wv = tid >> 6;      // wv 0..7
    const int q15 = lane & 15, g0 = lane >> 4;
    const int cW = wv * 48;                        // colgroup base (3 mf)

    f32x4 acc[3][4];
#pragma unroll
    for (int mf = 0; mf < 3; ++mf)
#pragma unroll
        for (int nf = 0; nf < 4; ++nf) acc[mf][nf] = (f32x4){0.f, 0.f, 0.f, 0.f};

    float4 st[2];
#define QKV_STAGE_LOAD(KC)                                                     \
    _Pragma("unroll") for (int i = 0; i < 2; ++i) {                            \
        int idx = tid + i * 512; int r = idx >> 4, c4 = idx & 15;              \
        int g = (KC) * 64 + c4 * 4;                                            \
        st[i] = (g <= 396) ? *reinterpret_cast<const float4*>(                 \
                                 &x[(size_t)(row0 + r) * 400 + g])             \
                           : make_float4(0.f, 0.f, 0.f, 0.f);                  \
    }
#define QKV_STAGE_WRITE(BUF)                                                   \
    _Pragma("unroll") for (int i = 0; i < 2; ++i) {                            \
        int idx = tid + i * 512; int r = idx >> 4, c4 = idx & 15;              \
        ushort4 hi4, lo4;                                                      \
        hi4.x = f2bf(st[i].x); lo4.x = f2bf(st[i].x - bfval(hi4.x));           \
        hi4.y = f2bf(st[i].y); lo4.y = f2bf(st[i].y - bfval(hi4.y));           \
        hi4.z = f2bf(st[i].z); lo4.z = f2bf(st[i].z - bfval(hi4.z));           \
        hi4.w = f2bf(st[i].w); lo4.w = f2bf(st[i].w - bfval(hi4.w));           \
        int off = r * 128 + ((c4 * 8) ^ ((r & 7) << 4));                       \
        *reinterpret_cast<ushort4*>((char*)xh_s[BUF] + off) = hi4;             \
        *reinterpret_cast<ushort4*>((char*)xl_s[BUF] + off) = lo4;             \
    }

    QKV_STAGE_LOAD(0)
    QKV_STAGE_WRITE(0)
    __syncthreads();                                   // buf0 published

    for (int kc = 0; kc < 7; ++kc) {
        const int cur = kc & 1;
        if (kc < 6) { QKV_STAGE_LOAD(kc + 1) }         // in flight under compute
#pragma unroll
        for (int k2 = 0; k2 < 2; ++k2) {
            const int k0 = kc * 64 + k2 * 32;
            bf16x8 bh[4], bl[4];
#pragma unroll
            for (int nf = 0; nf < 4; ++nf) {
                int row = nf * 16 + q15;
                int boff = row * 128 + ((k2 * 64 + g0 * 16) ^ ((row & 7) << 4));
                bh[nf] = *reinterpret_cast<const bf16x8*>((char*)xh_s[cur] + boff);
                bl[nf] = *reinterpret_cast<const bf16x8*>((char*)xl_s[cur] + boff);
            }
#pragma unroll
            for (int mf = 0; mf < 3; ++mf) {
                int col = cW + mf * 16 + q15;
                bf16x8 ah = *reinterpret_cast<const bf16x8*>(
                    wT_hi + (size_t)col * 448 + k0 + g0 * 8);
                bf16x8 al = *reinterpret_cast<const bf16x8*>(
                    wT_lo + (size_t)col * 448 + k0 + g0 * 8);
#pragma unroll
                for (int nf = 0; nf < 4; ++nf) {
                    acc[mf][nf] = MFMA16(ah, bh[nf], acc[mf][nf], 0, 0, 0);
                    acc[mf][nf] = MFMA16(ah, bl[nf], acc[mf][nf], 0, 0, 0);
                    acc[mf][nf] = MFMA16(al, bh[nf], acc[mf][nf], 0, 0, 0);
                }
            }
        }
        if (kc < 6) {
            QKV_STAGE_WRITE(cur ^ 1)                   // other buffer: no race with readers of cur
            __syncthreads();                           // publish buf kc+1
        }
    }

#pragma unroll
    for (int mf = 0; mf < 3; ++mf) {
        const int col0 = cW + mf * 16 + 4 * g0;
        const int c = col0 >> 7, h0 = col0 & 127;
#pragma unroll
        for (int nf = 0; nf < 4; ++nf) {
            const size_t row = (size_t)(row0 + nf * 16 + q15);
            if (c == 0) {
                ushort4 hi4, lo4;
#pragma unroll
                for (int r = 0; r < 4; ++r) {
                    float vf = acc[mf][nf][r];
                    ushort h = f2bf(vf);
                    ((ushort*)&hi4)[r] = h;
                    ((ushort*)&lo4)[r] = f2bf(vf - bfval(h));
                }
                *reinterpret_cast<ushort4*>(&q_hi[row * 128 + h0]) = hi4;
                *reinterpret_cast<ushort4*>(&q_lo[row * 128 + h0]) = lo4;
            } else if (c == 1) {
                ushort4 hi4;
#pragma unroll
                for (int r = 0; r < 4; ++r) ((ushort*)&hi4)[r] = f2bf(acc[mf][nf][r]);
                *reinterpret_cast<ushort4*>(&k_hi[row * 128 + h0]) = hi4;
            } else {
                const int keyl = (int)row & 2047;
#pragma unroll
                for (int jj = 0; jj < 4; ++jj) {
                    int h = h0 + jj;
                    if (h < 100)
                        vT[((size_t)bb * 112 + h) * 2048 + keyl] = f2bf(acc[mf][nf][jj]);
                }
            }
        }
    }
#undef QKV_STAGE_LOAD
#undef QKV_STAGE_WRITE
}

// ---------------- kernel 2: MFMA flash attention, QBLK=128, 8 waves, KV-split ----------------
template<bool PART>
__global__ __launch_bounds__(512, 2)
void k_flashT(const ushort* __restrict__ q_hi, const ushort* __restrict__ q_lo,
              const ushort* __restrict__ k_hi, const ushort* __restrict__ vT,
              float* __restrict__ outp, float2* __restrict__ mlP)
{
    __shared__ __align__(16) ushort k_s[64 * 128];    // 16 KB
    __shared__ __align__(16) ushort vT_s[112 * 64];   // 14 KB
    __shared__ __align__(16) ushort p_s[8][16 * 64];  // 16 KB

    const int id = blockIdx.x;                 // XCD-aware swizzle
    int b, qt, part;
    if (PART) {
        const int Lg = (id & 7) * 64 + (id >> 3);   // 512 blocks
        b = Lg >> 5; const int rem = Lg & 31; qt = rem >> 1; part = rem & 1;
    } else {
        const int Lg = (id & 7) * 32 + (id >> 3);   // 256 blocks
        b = Lg >> 4; qt = Lg & 15; part = 0;
    }
    const int q0 = qt * 128;
    const size_t bL = (size_t)b * L_SEQ;
    const int ktBeg = part * 16, ktEnd = PART ? ktBeg + 16 : 32;

    const int tid = threadIdx.x;
    const int lane = tid & 63, wv = tid >> 6;        // wv 0..7
    const int q15 = lane & 15, g0 = lane >> 4;

    bf16x8 qhf[4], qlf[4];
    {
        const ushort* qr = q_hi + (bL + q0 + 16 * wv + q15) * 128 + 8 * g0;
        const ushort* qs = q_lo + (bL + q0 + 16 * wv + q15) * 128 + 8 * g0;
#pragma unroll
        for (int kh = 0; kh < 4; ++kh) {
            qhf[kh] = *reinterpret_cast<const bf16x8*>(qr + 32 * kh);
            qlf[kh] = *reinterpret_cast<const bf16x8*>(qs + 32 * kh);
        }
    }

    float m_run = -1e30f, l_run = 0.f;
    f32x4 acc[7];
#pragma unroll
    for (int ht = 0; ht < 7; ++ht) acc[ht] = (f32x4){0.f, 0.f, 0.f, 0.f};

    for (int kt = ktBeg; kt < ktEnd; ++kt) {
        const int kb = kt * 64;
        __syncthreads();                               // prev compute done
        {   // stage K tile [64][128] bf16, swizzled granules (load->write inline)
            const char* khg = (const char*)(k_hi + (bL + kb) * 128);
            for (int n = tid; n < 1024; n += 512) {
                int key = n >> 4, gg = n & 15;
                uint4 d = *reinterpret_cast<const uint4*>(khg + n * 16);
                *reinterpret_cast<uint4*>((char*)k_s + key * 256 + (((gg ^ (key & 15))) << 4)) = d;
            }
            const char* vtg = (const char*)(vT + (size_t)b * 112 * 2048) + kb * 2;
            for (int n = tid; n < 896; n += 512) {
                int h = n >> 3, gg = n & 7;
                uint4 d = *reinterpret_cast<const uint4*>(vtg + h * 4096 + gg * 16);
                *reinterpret_cast<uint4*>((char*)vT_s + h * 128 + (((gg ^ (h & 7))) << 4)) = d;
            }
        }
        __syncthreads();

        // S^T = mfma(A=K, B=Q)
        f32x4 sacc[4];
        const int kx = q15 << 4;
        __builtin_amdgcn_s_setprio(1);
#pragma unroll
        for (int t = 0; t < 4; ++t) {
            sacc[t] = (f32x4){0.f, 0.f, 0.f, 0.f};
            const char* kr = (const char*)k_s + (t * 16 + q15) * 256;
#pragma unroll
            for (int kh = 0; kh < 4; ++kh) {
                bf16x8 kf = *reinterpret_cast<const bf16x8*>(kr + ((((kh << 2) + g0) << 4) ^ kx));
                sacc[t] = MFMA16(kf, qhf[kh], sacc[t], 0, 0, 0);
                sacc[t] = MFMA16(kf, qlf[kh], sacc[t], 0, 0, 0);
            }
        }
        __builtin_amdgcn_s_setprio(0);

        // online softmax, exp2 domain, defer-max (THR = 8*log2e)
        float mxl = -1e30f;
#pragma unroll
        for (int t = 0; t < 4; ++t)
#pragma unroll
            for (int r = 0; r < 4; ++r) mxl = fmaxf(mxl, sacc[t][r]);
        mxl = fmaxf(mxl, __shfl_xor(mxl, 16));
        mxl = fmaxf(mxl, __shfl_xor(mxl, 32));
        if (!__all(mxl - m_run <= DEFER_THR)) {
            float mn = fmaxf(m_run, mxl);
            float alpha = exp2_hw(m_run - mn);
            l_run *= alpha;
            m_run = mn;
            float alv[4];
#pragma unroll
            for (int r = 0; r < 4; ++r) alv[r] = __shfl(alpha, (g0 << 2) | r);
#pragma unroll
            for (int ht = 0; ht < 7; ++ht)
#pragma unroll
                for (int r = 0; r < 4; ++r) acc[ht][r] *= alv[r];
        }
        float lsum = 0.f;
        float p[4][4];
#pragma unroll
        for (int t = 0; t < 4; ++t)
#pragma unroll
            for (int r = 0; r < 4; ++r) {
                p[t][r] = exp2_hw(sacc[t][r] - m_run);
                lsum += p[t][r];
            }
        lsum += __shfl_xor(lsum, 16);
        lsum += __shfl_xor(lsum, 32);
        l_run += lsum;

        // P -> LDS (bf16 via v_cvt_pk_bf16_f32), per-wave region
        ushort* pw = p_s[wv];
        const int qb = q15 * 128;
#pragma unroll
        for (int t = 0; t < 4; ++t) {
            uint2 pv;
            asm("v_cvt_pk_bf16_f32 %0, %1, %2" : "=v"(pv.x) : "v"(p[t][0]), "v"(p[t][1]));
            asm("v_cvt_pk_bf16_f32 %0, %1, %2" : "=v"(pv.y) : "v"(p[t][2]), "v"(p[t][3]));
            int gw = (t << 1) + (g0 >> 1);
            *reinterpret_cast<uint2*>((char*)pw + qb + (((gw ^ (q15 & 7))) << 4)
                                      + ((g0 & 1) << 3)) = pv;
        }

        // PV
        bf16x8 pa0 = *reinterpret_cast<const bf16x8*>((char*)pw + qb + (((g0 ^ (q15 & 7))) << 4));
        bf16x8 pa1 = *reinterpret_cast<const bf16x8*>((char*)pw + qb + ((((4 + g0) ^ (q15 & 7))) << 4));
        __builtin_amdgcn_s_setprio(1);
#pragma unroll
        for (int ht = 0; ht < 7; ++ht) {
            const char* vr = (const char*)vT_s + (ht * 16 + q15) * 128;
            const int hx = ((ht * 16 + q15) & 7) << 4;
            bf16x8 vb0 = *reinterpret_cast<const bf16x8*>(vr + ((g0 << 4) ^ hx));
            bf16x8 vb1 = *reinterpret_cast<const bf16x8*>(vr + (((4 + g0) << 4) ^ hx));
            acc[ht] = MFMA16(pa0, vb0, acc[ht], 0, 0, 0);
            acc[ht] = MFMA16(pa1, vb1, acc[ht], 0, 0, 0);
        }
        __builtin_amdgcn_s_setprio(0);
    }

    if (PART) {
        float* ap = outp + (size_t)part * 3276800
                    + (bL + q0 + 16 * wv + (g0 << 2)) * 100;
#pragma unroll
        for (int ht = 0; ht < 7; ++ht) {
            int col = ht * 16 + q15;
            if (col < 100) {
#pragma unroll
                for (int r = 0; r < 4; ++r) ap[r * 100 + col] = acc[ht][r];
            }
        }
        if (g0 == 0) {
            float2 ml; ml.x = m_run; ml.y = l_run;   // m in log2 domain
            mlP[(size_t)part * 32768 + bL + q0 + 16 * wv + q15] = ml;
        }
    } else {
        float linv[4];
#pragma unroll
        for (int r = 0; r < 4; ++r) linv[r] = 1.0f / __shfl(l_run, (g0 << 2) | r);
#pragma unroll
        for (int ht = 0; ht < 7; ++ht) {
            int col = ht * 16 + q15;
            if (col < 100) {
                float* hp = outp + (bL + q0 + 16 * wv + (g0 << 2)) * 100 + col;
#pragma unroll
                for (int r = 0; r < 4; ++r) hp[r * 100] = acc[ht][r] * linv[r];
            }
        }
    }
}

// ---------------- kernel 3: MFMA hpool; COMBINE=true fuses the 2-way flash combine ----------------
template<bool COMBINE>
__global__ __launch_bounds__(512, 2)
void k_hpoolT(const float* __restrict__ accP, const float2* __restrict__ mlP,
              const ushort* __restrict__ WT_hi, const ushort* __restrict__ WT_lo,
              const float* __restrict__ b2,
              float* __restrict__ pmax, float* __restrict__ psum)
{
    __shared__ __align__(16) ushort hh_s[128 * 128];
    __shared__ __align__(16) ushort hl_s[128 * 128];
    __shared__ float pm_s[8][112], ps_s[8][112];
    const int blk = blockIdx.x;
    const int row0 = blk << 7;
    const int tid = threadIdx.x;
    const int lane = tid & 63, wv = tid >> 6;
    const int q15 = lane & 15, g0 = lane >> 4;
    const int wvM = wv >> 2, wvN = wv & 3;

    for (int i = 0; i < 7; ++i) {                 // stage head -> hi/lo LDS
        int idx = tid + i * 512;
        if (idx < 3200) {
            int r = idx / 25, cc = idx - r * 25;
            const size_t row = (size_t)(row0 + r);
            float4 t;
            if (COMBINE) {
                float2 ml1 = mlP[row], ml2 = mlP[32768 + row];
                float M = fmaxf(ml1.x, ml2.x);
                float w1 = exp2_hw(ml1.x - M), w2 = exp2_hw(ml2.x - M);
                float inv = 1.0f / (w1 * ml1.y + w2 * ml2.y);
                w1 *= inv; w2 *= inv;
                float4 a1 = *reinterpret_cast<const float4*>(&accP[row * 100 + cc * 4]);
                float4 a2 = *reinterpret_cast<const float4*>(&accP[3276800 + row * 100 + cc * 4]);
                t.x = w1 * a1.x + w2 * a2.x;
                t.y = w1 * a1.y + w2 * a2.y;
                t.z = w1 * a1.z + w2 * a2.z;
                t.w = w1 * a1.w + w2 * a2.w;
            } else {
                t = *reinterpret_cast<const float4*>(&accP[row * 100 + cc * 4]);
            }
            ushort4 hi4, lo4;
            hi4.x = f2bf(t.x); lo4.x = f2bf(t.x - bfval(hi4.x));
            hi4.y = f2bf(t.y); lo4.y = f2bf(t.y - bfval(hi4.y));
            hi4.z = f2bf(t.z); lo4.z = f2bf(t.z - bfval(hi4.z));
            hi4.w = f2bf(t.w); lo4.w = f2bf(t.w - bfval(hi4.w));
            int off = r * 256 + ((cc * 8) ^ ((r & 7) << 4));
            *reinterpret_cast<ushort4*>((char*)hh_s + off) = hi4;
            *reinterpret_cast<ushort4*>((char*)hl_s + off) = lo4;
        }
    }
    for (int idx = tid; idx < 896; idx += 512) {  // zero-pad k 100..127
        int r = idx / 7, c7 = idx - (idx / 7) * 7;
        int off = r * 256 + (((200 + c7 * 8)) ^ ((r & 7) << 4));
        ushort4 z = {0, 0, 0, 0};
        *reinterpret_cast<ushort4*>((char*)hh_s + off) = z;
        *reinterpret_cast<ushort4*>((char*)hl_s + off) = z;
    }
    __syncthreads();

    f32x4 acc[4][7];
#pragma unroll
    for (int mf = 0; mf < 4; ++mf)
#pragma unroll
        for (int nf = 0; nf < 7; ++nf) acc[mf][nf] = (f32x4){0.f, 0.f, 0.f, 0.f};

#pragma unroll
    for (int ks = 0; ks < 4; ++ks) {
        const int k0 = ks * 32;
        bf16x8 ah[4], al[4];
#pragma unroll
        for (int mf = 0; mf < 4; ++mf) {
            int rowL = wvM * 64 + mf * 16 + q15;
            int aoff = rowL * 256 + ((k0 * 2 + g0 * 16) ^ ((rowL & 7) << 4));
            ah[mf] = *reinterpret_cast<const bf16x8*>((char*)hh_s + aoff);
            al[mf] = *reinterpret_cast<const bf16x8*>((char*)hl_s + aoff);
        }
#pragma unroll
        for (int nf = 0; nf < 7; ++nf) {
            int col = wvN * 112 + nf * 16 + q15;
            bf16x8 bh = *reinterpret_cast<const bf16x8*>(WT_hi + col * 128 + k0 + g0 * 8);
            bf16x8 bl = *reinterpret_cast<const bf16x8*>(WT_lo + col * 128 + k0 + g0 * 8);
#pragma unroll
            for (int mf = 0; mf < 4; ++mf) {
                acc[mf][nf] = MFMA16(ah[mf], bh, acc[mf][nf], 0, 0, 0);
                acc[mf][nf] = MFMA16(ah[mf], bl, acc[mf][nf], 0, 0, 0);
                acc[mf][nf] = MFMA16(al[mf], bh, acc[mf][nf], 0, 0, 0);
            }
        }
    }

#pragma unroll
    for (int nf = 0; nf < 7; ++nf) {
        int col = wvN * 112 + nf * 16 + q15;
        float bv = (col < 400) ? b2[col] : 0.f;
        float mx = 0.f, sm = 0.f;
#pragma unroll
        for (int mf = 0; mf < 4; ++mf)
#pragma unroll
            for (int r = 0; r < 4; ++r) {
                float hv = fmaxf(acc[mf][nf][r] + bv, 0.f);
                mx = fmaxf(mx, hv); sm += hv;
            }
        mx = fmaxf(mx, __shfl_xor(mx, 16));
        mx = fmaxf(mx, __shfl_xor(mx, 32));
        sm += __shfl_xor(sm, 16);
        sm += __shfl_xor(sm, 32);
        if (g0 == 0) {
            pm_s[wv][nf * 16 + q15] = mx;
            ps_s[wv][nf * 16 + q15] = sm;
        }
    }
    __syncthreads();
    if (tid < 448) {
        int wn = tid / 112, cc = tid - wn * 112;
        float mx = fmaxf(pm_s[wn][cc], pm_s[4 + wn][cc]);
        float sm = ps_s[wn][cc] + ps_s[4 + wn][cc];
        if (tid < 400) {
            pmax[blk * 400 + tid] = mx;
            psum[blk * 400 + tid] = sm;
        }
    }
}

// ---------------- kernel 4a: reduce 16 partials -> zin[16][800] ----------------
__global__ __launch_bounds__(512)
void k_reduce(const float* __restrict__ pmax, const float* __restrict__ psum,
              float* __restrict__ zin)
{
    const int b = blockIdx.x, c = threadIdx.x;
    if (c < 400) {
        float m = 0.f, s = 0.f;
#pragma unroll
        for (int tt = 0; tt < 16; ++tt) {
            m = fmaxf(m, pmax[(b * 16 + tt) * 400 + c]);
            s += psum[(b * 16 + tt) * 400 + c];
        }
        zin[b * 800 + c] = m;
        zin[b * 800 + 400 + c] = s * (1.0f / 2048.0f);
    }
}

// ---------------- kernel 4b: z1 = relu(zin @ w3 + b3), split-k x8 ----------------
__global__ __launch_bounds__(512)
void k_mlp1(const float* __restrict__ zin, const float* __restrict__ w3,
            const float* __restrict__ b3, float* __restrict__ z1)
{
    __shared__ float zs[800];
    __shared__ float red[8][64];
    const int cb = blockIdx.x, b = blockIdx.y;
    const int tid = threadIdx.x;
    const int c = tid & 63, kk = tid >> 6;
    const int col = cb * 64 + c;
    for (int i = tid; i < 800; i += 512) zs[i] = zin[b * 800 + i];
    __syncthreads();
    float acc = 0.f;
    const int k0 = kk * 100;
#pragma unroll 4
    for (int k = 0; k < 100; ++k)
        acc += zs[k0 + k] * w3[(k0 + k) * 512 + col];
    red[kk][c] = acc;
    __syncthreads();
    if (kk == 0) {
        float a = b3[col];
#pragma unroll
        for (int g = 0; g < 8; ++g) a += red[g][c];
        z1[b * 512 + col] = fmaxf(a, 0.f);
    }
}

// ---------------- kernel 4c: out = relu(z1 @ w4 + b4), split-k x8 ----------------
__global__ __launch_bounds__(512)
void k_mlp2(const float* __restrict__ z1, const float* __restrict__ w4,
            const float* __restrict__ b4, float* __restrict__ out)
{
    __shared__ float zs[512];
    __shared__ float red[8][64];
    const int cb = blockIdx.x, b = blockIdx.y;
    const int tid = threadIdx.x;
    const int c = tid & 63, kk = tid >> 6;
    const int col = cb * 64 + c;
    if (tid < 512) zs[tid] = z1[b * 512 + tid];
    __syncthreads();
    float acc = 0.f;
    const int k0 = kk * 64;
#pragma unroll 4
    for (int k = 0; k < 64; ++k)
        acc += zs[k0 + k] * w4[(k0 + k) * 256 + col];
    red[kk][c] = acc;
    __syncthreads();
    if (kk == 0) {
        float a = b4[col];
#pragma unroll
        for (int g = 0; g < 8; ++g) a += red[g][c];
        out[b * 256 + col] = fmaxf(a, 0.f);
    }
}

extern "C" void kernel_launch(void* const* d_in, const int* in_sizes, int n_in,
                              void* d_out, int out_size, void* d_ws, size_t ws_size,
                              hipStream_t stream) {
    (void)in_sizes; (void)n_in; (void)out_size;
    const float* x     = (const float*)d_in[0];
    const float* kw    = (const float*)d_in[1];
    const float* dense = (const float*)d_in[2];
    const float* w2    = (const float*)d_in[3];
    const float* b2    = (const float*)d_in[4];
    const float* w3    = (const float*)d_in[5];
    const float* b3    = (const float*)d_in[6];
    const float* w4    = (const float*)d_in[7];
    const float* b4    = (const float*)d_in[8];
    float* ws = (float*)d_ws;
    // fixed layout (float units):
    ushort* q_hi = (ushort*)(ws);                 // [32768][128] bf16
    ushort* q_lo = (ushort*)(ws + 2097152);
    ushort* k_hi = (ushort*)(ws + 4194304);
    ushort* vT   = (ushort*)(ws + 6291456);       // [16][112][2048] bf16
    float*  head = ws + 8126464;                  // [32768][100] f32 (= accP part 0)
    ushort* wT_hi = (ushort*)(ws + 8126464);      // overlays head; dead before flash
    ushort* wT_lo = (ushort*)(ws + 8212480);
    float*  pmax = ws;                            // overlays q_hi (dead after flash)
    float*  psum = ws + 2097152;
    float*  zin  = ws + 4194304;
    float*  z1   = ws + 4207104;
    float*  outp = (float*)d_out;

    // split path needs accP[2][32768][100] (at head) + mlP + WT beyond it
    const bool split = ws_size >= (size_t)14999552 * sizeof(float);
    float*  accP  = head;                                 // part0 == head
    float2* mlP   = (float2*)(ws + 14680064);
    ushort* WT_hi = (ushort*)(ws + (split ? 14942208 : 11403264));
    ushort* WT_lo = WT_hi + 57344;

    k_prep  <<<dim3(608),      dim3(256), 0, stream>>>(dense, w2, kw,
                                                       WT_hi, WT_lo, wT_hi, wT_lo);
    k_qkv   <<<dim3(512),      dim3(512), 0, stream>>>(x, wT_hi, wT_lo,
                                                       q_hi, q_lo, k_hi, vT);
    if (split) {
        k_flashT<true>  <<<dim3(512),  dim3(512), 0, stream>>>(q_hi, q_lo, k_hi, vT,
                                                               accP, mlP);
        k_hpoolT<true>  <<<dim3(256),  dim3(512), 0, stream>>>(accP, mlP,
                                                               WT_hi, WT_lo, b2,
                                                               pmax, psum);
    } else {
        k_flashT<false> <<<dim3(256),  dim3(512), 0, stream>>>(q_hi, q_lo, k_hi, vT,
                                                               head, nullptr);
        k_hpoolT<false> <<<dim3(256),  dim3(512), 0, stream>>>(head, nullptr,
                                                               WT_hi, WT_lo, b2,
                                                               pmax, psum);
    }
    k_reduce<<<dim3(16),       dim3(512), 0, stream>>>(pmax, psum, zin);
    k_mlp1  <<<dim3(8, 16),    dim3(512), 0, stream>>>(zin, w3, b3, z1);
    k_mlp2  <<<dim3(4, 16),    dim3(512), 0, stream>>>(z1, w4, b4, outp);
}